// Round 6
// baseline (182.260 us; speedup 1.0000x reference)
//
#include <hip/hip_runtime.h>

// 3D LUT trilinear apply — round 10.
// R9 post-mortem: within-iteration ILP surgery = -1.4us (182.0, best).
// Kernel ~54us vs ~32-35us pipe-max. R7 counters: nothing >40% utilized
// (HBM 37%, VALU 35%, LDS-conflict 13%, occ 32%) => latency-bound, overlap
// deficit. TLP is hard-capped (143.7KiB LDS -> 16 waves/CU), but VGPR=56
// of ~512 free => buy overlap with ILP DEPTH instead: full cross-iteration
// software pipeline. Steady state of iter j:
//   prefetch inputs(j+2) [VMEM] ; gather(j+1) [DS] ; math+store(j) [VALU]
// -> every consumed value was produced >=1 full iteration earlier; DS
// latency covered by ~1000cy of math, VMEM by two iterations.
// Single change vs R9 (fill/math/addressing identical). G[2][4] gather
// state, static indices via full unroll.
// Predict: kernel 38-44 -> dur 166-173. Null (179-184) => compiler/wave
// phase-lock wins; next axis = VALU reduction (pk-f16 math).

namespace {

constexpr int DIM    = 33;
constexpr int WH     = 1024 * 1024;     // 2^20
constexpr int BATCH  = 8;
constexpr int NPIX   = BATCH * WH;      // 8388608
constexpr int LUT_N  = DIM * DIM * DIM; // 35937

constexpr int BLOCKS  = 256;
constexpr int TPB     = 1024;
constexpr int NTHREAD = BLOCKS * TPB;        // 262144
constexpr int NITER   = NPIX / 4 / NTHREAD;  // exactly 8
static_assert(NTHREAD * 4 == WH, "address collapse relies on this");

using f4 = __attribute__((ext_vector_type(4))) float;

__device__ __forceinline__ f4 nt_load4(const float* p) {
    return __builtin_nontemporal_load((const f4*)p);
}
__device__ __forceinline__ void st4(float* p, f4 v) {
    *(f4*)p = v;   // plain cached store (R6 A/B: == NT)
}

struct Gath {
    unsigned int q0, q1, q2, q3, q4, q5, q6, q7;
    float fr, fg, fb;
};

__device__ __forceinline__ Gath gather_px(
    const unsigned int* lds_lut, float r, float g, float b)
{
    const float inv_binsize = 32.0f / 1.0001f;
    float sr = r * inv_binsize;
    float sg = g * inv_binsize;
    float sb = b * inv_binsize;
    // x in [0,1) => scaled in [0,31.9968): trunc==floor, idx+1 <= 32 in-bounds.
    int ir = (int)sr, ig = (int)sg, ib = (int)sb;

    Gath G;
    G.fr = sr - (float)ir;
    G.fg = sg - (float)ig;
    G.fb = sb - (float)ib;

    int base  = ib * (DIM * DIM) + ig * DIM + ir;
    int base2 = base + DIM * DIM;
    // pairs (+0,+1), (+33,+34) -> ds_read2_b32 friendly
    G.q0 = lds_lut[base];
    G.q1 = lds_lut[base + 1];
    G.q2 = lds_lut[base + DIM];
    G.q3 = lds_lut[base + DIM + 1];
    G.q4 = lds_lut[base2];
    G.q5 = lds_lut[base2 + 1];
    G.q6 = lds_lut[base2 + DIM];
    G.q7 = lds_lut[base2 + DIM + 1];
    return G;
}

__device__ __forceinline__ void math_px(
    const Gath& G, float& outR, float& outG, float& outB)
{
    float fr = G.fr, fg = G.fg, fb = G.fb;
    float w00 = (1.f - fg) * (1.f - fb);
    float w10 = fg * (1.f - fb);
    float w01 = (1.f - fg) * fb;
    float w11 = fg * fb;
    float w000 = (1.f - fr) * w00, w100 = fr * w00;
    float w010 = (1.f - fr) * w10, w110 = fr * w10;
    float w001 = (1.f - fr) * w01, w101 = fr * w01;
    float w011 = (1.f - fr) * w11, w111 = fr * w11;

    float accR, accG, accB;
    // q>>20 needs no mask (bits 30-31 zero); (q>>10)&1023 -> v_bfe
    accR  = w000 * (float)(G.q0 & 1023u);
    accG  = w000 * (float)((G.q0 >> 10) & 1023u);
    accB  = w000 * (float)(G.q0 >> 20);
    accR += w100 * (float)(G.q1 & 1023u);
    accG += w100 * (float)((G.q1 >> 10) & 1023u);
    accB += w100 * (float)(G.q1 >> 20);
    accR += w010 * (float)(G.q2 & 1023u);
    accG += w010 * (float)((G.q2 >> 10) & 1023u);
    accB += w010 * (float)(G.q2 >> 20);
    accR += w110 * (float)(G.q3 & 1023u);
    accG += w110 * (float)((G.q3 >> 10) & 1023u);
    accB += w110 * (float)(G.q3 >> 20);
    accR += w001 * (float)(G.q4 & 1023u);
    accG += w001 * (float)((G.q4 >> 10) & 1023u);
    accB += w001 * (float)(G.q4 >> 20);
    accR += w101 * (float)(G.q5 & 1023u);
    accG += w101 * (float)((G.q5 >> 10) & 1023u);
    accB += w101 * (float)(G.q5 >> 20);
    accR += w011 * (float)(G.q6 & 1023u);
    accG += w011 * (float)((G.q6 >> 10) & 1023u);
    accB += w011 * (float)(G.q6 >> 20);
    accR += w111 * (float)(G.q7 & 1023u);
    accG += w111 * (float)((G.q7 >> 10) & 1023u);
    accB += w111 * (float)(G.q7 >> 20);

    const float inv1023 = 1.0f / 1023.0f;
    outR = accR * inv1023;
    outG = accG * inv1023;
    outB = accB * inv1023;
}

__global__ __launch_bounds__(TPB, 4) void lut3d_lds_kernel(
    const float* __restrict__ lut, const float* __restrict__ x,
    float* __restrict__ out)
{
    __shared__ unsigned int lds_lut[LUT_N]; // 143748 B -> 1 block/CU, 16 waves

    const int tid = threadIdx.x;
    const int gid = blockIdx.x * TPB + tid;
    const int p0  = gid * 4;                 // iteration-invariant plane offset
    const float* xp = x + p0;
    float*       op = out + p0;

    // ---- prologue: inputs for iters 0 and 1 issued BEFORE the LDS fill.
    f4 R[2], G[2], B[2];
    R[0] = nt_load4(xp);
    G[0] = nt_load4(xp + WH);
    B[0] = nt_load4(xp + 2 * WH);
    R[1] = nt_load4(xp + 3 * WH);
    G[1] = nt_load4(xp + 4 * WH);
    B[1] = nt_load4(xp + 5 * WH);

    // ---- LDS fill: quantize f32 SoA LUT -> 10:10:10 u32.
    // 35937 = 35*1024 + 97: branch-free main loop + tail, coalesced.
#pragma unroll
    for (int k = 0; k < 35; ++k) {
        int i = tid + k * TPB;
        float r = lut[i];
        float g = lut[LUT_N + i];
        float b = lut[2 * LUT_N + i];
        unsigned int qr = (unsigned int)__float2int_rn(__saturatef(r) * 1023.0f);
        unsigned int qg = (unsigned int)__float2int_rn(__saturatef(g) * 1023.0f);
        unsigned int qb = (unsigned int)__float2int_rn(__saturatef(b) * 1023.0f);
        lds_lut[i] = qr | (qg << 10) | (qb << 20);
    }
    if (tid < LUT_N - 35 * TPB) {
        int i = tid + 35 * TPB;
        float r = lut[i];
        float g = lut[LUT_N + i];
        float b = lut[2 * LUT_N + i];
        unsigned int qr = (unsigned int)__float2int_rn(__saturatef(r) * 1023.0f);
        unsigned int qg = (unsigned int)__float2int_rn(__saturatef(g) * 1023.0f);
        unsigned int qb = (unsigned int)__float2int_rn(__saturatef(b) * 1023.0f);
        lds_lut[i] = qr | (qg << 10) | (qb << 20);
    }
    __syncthreads();

    // ---- cross-iteration software pipeline.
    // State: G[s][px] = gathered corners for iteration with (it&1)==s.
    Gath Gq[2][4];
#pragma unroll
    for (int l = 0; l < 4; ++l)
        Gq[0][l] = gather_px(lds_lut, R[0][l], G[0][l], B[0][l]);

#pragma unroll
    for (int it = 0; it < NITER; ++it) {
        const int s  = it & 1;        // compile-time after full unroll
        const int sn = s ^ 1;

        // 1) prefetch inputs for iter it+2 into the input slot freed when
        //    iter it's inputs were gathered (last iteration / prologue).
        if (it + 2 < NITER) {
            const float* xn = xp + (size_t)(it + 2) * 3 * WH;
            R[s] = nt_load4(xn);
            G[s] = nt_load4(xn + WH);
            B[s] = nt_load4(xn + 2 * WH);
        }

        // 2) issue iter it+1's gathers now — their latency is covered by
        //    the full math block below (~12 independent FMA chains).
        if (it + 1 < NITER) {
#pragma unroll
            for (int l = 0; l < 4; ++l)
                Gq[sn][l] = gather_px(lds_lut, R[sn][l], G[sn][l], B[sn][l]);
        }

        // 3) math + store for iter it (uses gathers issued one iter ago).
        f4 oR, oG, oB;
#pragma unroll
        for (int l = 0; l < 4; ++l) {
            float tR, tG, tB;
            math_px(Gq[s][l], tR, tG, tB);
            oR[l] = tR; oG[l] = tG; oB[l] = tB;
        }

        float* ob = op + (size_t)it * 3 * WH;  // compile-time offset per iter
        st4(ob,          oR);
        st4(ob + WH,     oG);
        st4(ob + 2 * WH, oB);
    }
}

} // namespace

extern "C" void kernel_launch(void* const* d_in, const int* in_sizes, int n_in,
                              void* d_out, int out_size, void* d_ws, size_t ws_size,
                              hipStream_t stream) {
    const float* lut = (const float*)d_in[0];
    const float* x   = (const float*)d_in[1];
    float*       out = (float*)d_out;
    (void)d_ws; (void)ws_size;

    lut3d_lds_kernel<<<BLOCKS, TPB, 0, stream>>>(lut, x, out);
}